// Round 2
// baseline (47.471 us; speedup 1.0000x reference)
//
#include <hip/hip_runtime.h>
#include <math.h>

// DeepHit loss: -mean(log(prob+eps)) + 0.5 * mean_pair relu(risk_j - risk_i + 0.1)
// B=8192 rows, T=256 time bins.
//
// Structure:
//  k1 (row_kernel):  1 wave per row, float4 loads, shuffle reductions only.
//                    Produces pack[b] = {risk_sum, (float)t} and rowll[b].
//  k2 (rank_kernel): 32x32 tile grid over index upper-triangle; j-tile staged
//                    in LDS as float2; branchless inner loop; per-block partial.
//  k3 (final_kernel): deterministic single-block reduce -> out[0].

#define B_ROWS 8192
#define T_COLS 256
#define NTILE  32           // B_ROWS / 256

__global__ __launch_bounds__(256) void row_kernel(
    const float* __restrict__ risk_probs,   // [B, T]
    const int*   __restrict__ times,        // [B]
    const int*   __restrict__ events,       // [B]
    float2* __restrict__ pack,              // [B] out: {risk_sum, t}
    float*  __restrict__ rowll)             // [B] out: log(prob + eps)
{
    const int wid  = threadIdx.x >> 6;      // wave in block: 0..3
    const int lane = threadIdx.x & 63;
    const int row  = (blockIdx.x << 2) + wid;

    const float4 h4 = reinterpret_cast<const float4*>(risk_probs)[row * 64 + lane];

    int tb = times[row];
    tb = max(0, min(tb, T_COLS - 1));

    // risk = sum_t h
    float rs = (h4.x + h4.y) + (h4.z + h4.w);

    // partial product of (1 - h_i) for i < tb   (S(t-1), S(-1)=1)
    const int base = lane << 2;
    float p = 1.0f;
    p *= (base + 0 < tb) ? (1.0f - h4.x) : 1.0f;
    p *= (base + 1 < tb) ? (1.0f - h4.y) : 1.0f;
    p *= (base + 2 < tb) ? (1.0f - h4.z) : 1.0f;
    p *= (base + 3 < tb) ? (1.0f - h4.w) : 1.0f;

    #pragma unroll
    for (int off = 32; off > 0; off >>= 1) {
        rs += __shfl_down(rs, off, 64);
        p  *= __shfl_down(p,  off, 64);
    }

    if (lane == 0) {
        const float ht = risk_probs[row * T_COLS + tb];   // L1 hit
        const int   ev = events[row];
        // event: S(t-1)*h(t) ; censored: S(t) = S(t-1)*(1-h(t))
        const float prob = p * (ev == 1 ? ht : (1.0f - ht));
        pack[row]  = make_float2(rs, (float)tb);
        rowll[row] = logf(prob + 1e-8f);
    }
}

// Block (ti,tj): i in [ti*256, ti*256+256), j in [tj*256, ...). Only tj>=ti
// does work; all blocks write their partial every call (ws is never
// re-poisoned, but stale values would otherwise persist).
__global__ __launch_bounds__(256) void rank_kernel(
    const float2* __restrict__ pack,         // [B] {risk, t}
    const int*    __restrict__ events,       // [B]
    float*        __restrict__ rank_partial, // [NTILE*NTILE]
    unsigned int* __restrict__ cnt_partial)  // [NTILE*NTILE]
{
    const int ti  = blockIdx.x;
    const int tj  = blockIdx.y;
    const int tid = threadIdx.x;
    const int pidx = ti * NTILE + tj;

    __shared__ float2 sj[256];

    float        sum = 0.0f;
    unsigned int cnt = 0u;

    if (tj >= ti) {
        const int i = ti * 256 + tid;
        const float2 pi = pack[i];
        const int    ei = events[i];
        const float  ci    = pi.x - 0.1f;                 // risk_i - margin
        const float  tieff = (ei == 1) ? pi.y : 1.0e9f;   // disable non-events

        sj[tid] = pack[tj * 256 + tid];
        __syncthreads();

        if (tj > ti) {
            // all j in tile have index > i: no index check
            #pragma unroll 4
            for (int k = 0; k < 256; ++k) {
                const float2 v = sj[k];               // LDS broadcast
                const bool ok = (v.y > tieff);
                sum += ok ? fmaxf(v.x - ci, 0.0f) : 0.0f;
                cnt += ok ? 1u : 0u;
            }
        } else {
            // diagonal tile: j = tj*256 + k must be > i  ->  k > tid
            for (int k = tid + 1; k < 256; ++k) {
                const float2 v = sj[k];
                const bool ok = (v.y > tieff);
                sum += ok ? fmaxf(v.x - ci, 0.0f) : 0.0f;
                cnt += ok ? 1u : 0u;
            }
        }
    }

    // deterministic block reduce: wave shuffle + 4-way LDS combine
    #pragma unroll
    for (int off = 32; off > 0; off >>= 1) {
        sum += __shfl_down(sum, off, 64);
        cnt += __shfl_down((int)cnt, off, 64);
    }
    __shared__ float        wsums[4];
    __shared__ unsigned int wcnts[4];
    if ((tid & 63) == 0) { wsums[tid >> 6] = sum; wcnts[tid >> 6] = cnt; }
    __syncthreads();
    if (tid == 0) {
        rank_partial[pidx] = (wsums[0] + wsums[1]) + (wsums[2] + wsums[3]);
        cnt_partial[pidx]  = wcnts[0] + wcnts[1] + wcnts[2] + wcnts[3];
    }
}

__global__ __launch_bounds__(256) void final_kernel(
    const float*        __restrict__ rowll,         // [B]
    const float*        __restrict__ rank_partial,  // [NTILE*NTILE]
    const unsigned int* __restrict__ cnt_partial,   // [NTILE*NTILE]
    float* __restrict__ out)
{
    const int tid = threadIdx.x;

    float a = 0.0f;
    for (int k = tid; k < B_ROWS; k += 256) a += rowll[k];

    float        b = 0.0f;
    unsigned int c = 0u;
    for (int k = tid; k < NTILE * NTILE; k += 256) {
        b += rank_partial[k];
        c += cnt_partial[k];
    }

    #pragma unroll
    for (int off = 32; off > 0; off >>= 1) {
        a += __shfl_down(a, off, 64);
        b += __shfl_down(b, off, 64);
        c += __shfl_down((int)c, off, 64);
    }

    __shared__ float        sa[4], sb[4];
    __shared__ unsigned int sc[4];
    if ((tid & 63) == 0) { sa[tid >> 6] = a; sb[tid >> 6] = b; sc[tid >> 6] = c; }
    __syncthreads();

    if (tid == 0) {
        const float        lls  = (sa[0] + sa[1]) + (sa[2] + sa[3]);
        const float        rsum = (sb[0] + sb[1]) + (sb[2] + sb[3]);
        const unsigned int n    = sc[0] + sc[1] + sc[2] + sc[3];
        const float ll   = -lls / (float)B_ROWS;
        const float rank = (n > 0u) ? (rsum / (float)n) : 0.0f;
        out[0] = ll + 0.5f * rank;
    }
}

extern "C" void kernel_launch(void* const* d_in, const int* in_sizes, int n_in,
                              void* d_out, int out_size, void* d_ws, size_t ws_size,
                              hipStream_t stream) {
    const float* risk_probs = (const float*)d_in[0];
    const int*   times      = (const int*)d_in[1];
    const int*   events     = (const int*)d_in[2];
    float*       out        = (float*)d_out;

    // Workspace layout (~104 KiB):
    float2*       pack         = (float2*)d_ws;                          // [B]
    float*        rowll        = (float*)(pack + B_ROWS);                // [B]
    float*        rank_partial = rowll + B_ROWS;                         // [NTILE*NTILE]
    unsigned int* cnt_partial  = (unsigned int*)(rank_partial + NTILE * NTILE);

    row_kernel<<<B_ROWS / 4, 256, 0, stream>>>(risk_probs, times, events, pack, rowll);
    rank_kernel<<<dim3(NTILE, NTILE), 256, 0, stream>>>(pack, events, rank_partial, cnt_partial);
    final_kernel<<<1, 256, 0, stream>>>(rowll, rank_partial, cnt_partial, out);
}